// Round 5
// baseline (113.821 us; speedup 1.0000x reference)
//
#include <hip/hip_runtime.h>

// SemiSparseCRFLoss on MI355X — R5: vertical 2-row pairing.
// Each thread owns rows (h, h+1) of one 8-px column segment in ONE batch:
// the middle row is loaded once and used as both "next" for row A and
// "cur" for row B (24% fewer loads), all under a single block-uniform
// selection branch (max MLP). ~100us of dur_us is fixed harness reset;
// this targets the ~8us latency-bound map kernel.

#define BATCH 16
#define HGT 512
#define WID 512
#define HW (HGT * WID)
#define SEG 8
#define NBLOCK 1024                  // 64 blocks/batch; 256 thr = 128 row-pairs... see mapping
// per batch: 256 row-pairs * 64 col-segs = 16384 threads = 64 blocks

__global__ __launch_bounds__(256) void crf_map(
        const float* __restrict__ y_pr,
        const float* __restrict__ image,
        const int* __restrict__ image_class,
        double* __restrict__ partial) {
    const float inv2s2 = 22.2222222f;    // 1/(2*0.15^2)
    const float wxy1 = 0.60653066f;      // exp(-1/2): shifts (0,1),(1,0)
    const float wxy2 = 0.36787944f;      // exp(-1):   shifts (1,1),(1,-1)

    const int b = blockIdx.x >> 6;       // wave-uniform batch, 64 blocks/batch
    double local = 0.0;

    if (image_class[b] != 0) {           // block-uniform skip
        const int tid = blockIdx.x * 256 + threadIdx.x;
        const int q = tid & 16383;       // within-batch index, 2^14
        const int rp = q >> 6;           // row pair 0..255
        const int w0 = (q & 63) * SEG;   // col start
        const int h = rp * 2;            // rows h, h+1 (h <= 510)
        const int hw = h * WID + w0;
        const bool left = (w0 > 0);
        const bool right = (w0 + SEG < WID);
        const bool hnB = (rp < 255);     // row h+2 exists

        const float* __restrict__ yb = y_pr + (size_t)b * 2 * HW + HW; // ch 1
        const float* __restrict__ ib = image + (size_t)b * 3 * HW;

        // d2 accumulators: row A (h) and row B (h+1), 4 shifts x 8 px
        float Ar[8], Ad[8], Adr[8], Adl[8];
        float Br[8], Bd[8], Bdr[8], Bdl[8];
        #pragma unroll
        for (int j = 0; j < 8; j++) {
            Ar[j]=0.f; Ad[j]=0.f; Adr[j]=0.f; Adl[j]=0.f;
            Br[j]=0.f; Bd[j]=0.f; Bdr[j]=0.f; Bdl[j]=0.f;
        }

        #pragma unroll
        for (int c = 0; c < 3; c++) {
            const float* __restrict__ p = ib + c * HW + hw;
            float a[9];    // row h,   cols w0   .. w0+8
            float m[10];   // row h+1, cols w0-1 .. w0+8
            float n[10];   // row h+2, cols w0-1 .. w0+8
            {
                float4 a0 = *(const float4*)(p);
                float4 a1 = *(const float4*)(p + 4);
                a[0]=a0.x; a[1]=a0.y; a[2]=a0.z; a[3]=a0.w;
                a[4]=a1.x; a[5]=a1.y; a[6]=a1.z; a[7]=a1.w;
                a[8] = right ? p[8] : 0.f;
            }
            {
                float4 b0 = *(const float4*)(p + WID);
                float4 b1 = *(const float4*)(p + WID + 4);
                m[0] = left ? p[WID - 1] : 0.f;
                m[1]=b0.x; m[2]=b0.y; m[3]=b0.z; m[4]=b0.w;
                m[5]=b1.x; m[6]=b1.y; m[7]=b1.z; m[8]=b1.w;
                m[9] = right ? p[WID + 8] : 0.f;
            }
            if (hnB) {
                float4 c0 = *(const float4*)(p + 2 * WID);
                float4 c1 = *(const float4*)(p + 2 * WID + 4);
                n[0] = left ? p[2 * WID - 1] : 0.f;
                n[1]=c0.x; n[2]=c0.y; n[3]=c0.z; n[4]=c0.w;
                n[5]=c1.x; n[6]=c1.y; n[7]=c1.z; n[8]=c1.w;
                n[9] = right ? p[2 * WID + 8] : 0.f;
            } else {
                #pragma unroll
                for (int k = 0; k < 10; k++) n[k] = 0.f;
            }
            #pragma unroll
            for (int j = 0; j < 8; j++) {
                // row A: cur=a[j], next-row window m[j..j+2]
                float t;
                t = a[j] - a[j + 1];      Ar[j]  += t * t;
                t = a[j] - m[j + 1];      Ad[j]  += t * t;
                t = a[j] - m[j + 2];      Adr[j] += t * t;
                t = a[j] - m[j];          Adl[j] += t * t;
                // row B: cur=m[j+1], next-row window n[j..j+2]
                t = m[j + 1] - m[j + 2];  Br[j]  += t * t;
                t = m[j + 1] - n[j + 1];  Bd[j]  += t * t;
                t = m[j + 1] - n[j + 2];  Bdr[j] += t * t;
                t = m[j + 1] - n[j];      Bdl[j] += t * t;
            }
        }

        // y rows
        float ya[9], ym[10], yn[10];
        {
            const float* __restrict__ p = yb + hw;
            float4 a0 = *(const float4*)(p);
            float4 a1 = *(const float4*)(p + 4);
            ya[0]=a0.x; ya[1]=a0.y; ya[2]=a0.z; ya[3]=a0.w;
            ya[4]=a1.x; ya[5]=a1.y; ya[6]=a1.z; ya[7]=a1.w;
            ya[8] = right ? p[8] : 0.f;
            float4 b0 = *(const float4*)(p + WID);
            float4 b1 = *(const float4*)(p + WID + 4);
            ym[0] = left ? p[WID - 1] : 0.f;
            ym[1]=b0.x; ym[2]=b0.y; ym[3]=b0.z; ym[4]=b0.w;
            ym[5]=b1.x; ym[6]=b1.y; ym[7]=b1.z; ym[8]=b1.w;
            ym[9] = right ? p[WID + 8] : 0.f;
            if (hnB) {
                float4 c0 = *(const float4*)(p + 2 * WID);
                float4 c1 = *(const float4*)(p + 2 * WID + 4);
                yn[0] = left ? p[2 * WID - 1] : 0.f;
                yn[1]=c0.x; yn[2]=c0.y; yn[3]=c0.z; yn[4]=c0.w;
                yn[5]=c1.x; yn[6]=c1.y; yn[7]=c1.z; yn[8]=c1.w;
                yn[9] = right ? p[2 * WID + 8] : 0.f;
            } else {
                #pragma unroll
                for (int k = 0; k < 10; k++) yn[k] = 0.f;
            }
        }

        float s = 0.f;
        #pragma unroll
        for (int j = 0; j < 8; j++) {
            const bool rj = (j < 7) || right;
            const bool lj = (j > 0) || left;
            float dy;
            // ---- row A (h): down-row always valid (h+1 <= 511) ----
            if (rj) {                                  // (0,1)
                dy = ya[j] - ya[j + 1];
                s += (__expf(-Ar[j] * inv2s2) * wxy1 - 0.01f) * dy * dy;
            }
            {                                          // (1,0)
                dy = ya[j] - ym[j + 1];
                s += (__expf(-Ad[j] * inv2s2) * wxy1 - 0.01f) * dy * dy;
            }
            if (rj) {                                  // (1,1)
                dy = ya[j] - ym[j + 2];
                s += (__expf(-Adr[j] * inv2s2) * wxy2 - 0.01f) * dy * dy;
            }
            if (lj) {                                  // (1,-1)
                dy = ya[j] - ym[j];
                s += (__expf(-Adl[j] * inv2s2) * wxy2 - 0.01f) * dy * dy;
            }
            // ---- row B (h+1) ----
            if (rj) {                                  // (0,1)
                dy = ym[j + 1] - ym[j + 2];
                s += (__expf(-Br[j] * inv2s2) * wxy1 - 0.01f) * dy * dy;
            }
            if (hnB) {
                {                                      // (1,0)
                    dy = ym[j + 1] - yn[j + 1];
                    s += (__expf(-Bd[j] * inv2s2) * wxy1 - 0.01f) * dy * dy;
                }
                if (rj) {                              // (1,1)
                    dy = ym[j + 1] - yn[j + 2];
                    s += (__expf(-Bdr[j] * inv2s2) * wxy2 - 0.01f) * dy * dy;
                }
                if (lj) {                              // (1,-1)
                    dy = ym[j + 1] - yn[j];
                    s += (__expf(-Bdl[j] * inv2s2) * wxy2 - 0.01f) * dy * dy;
                }
            }
        }
        local = (double)s;
    }

    // wave64 reduction
    for (int off = 32; off > 0; off >>= 1)
        local += __shfl_down(local, off);

    __shared__ double sdata[4];
    const int lane = threadIdx.x & 63;
    const int wv = threadIdx.x >> 6;
    if (lane == 0) sdata[wv] = local;
    __syncthreads();
    if (threadIdx.x == 0)
        partial[blockIdx.x] = sdata[0] + sdata[1] + sdata[2] + sdata[3];
}

__global__ __launch_bounds__(256) void crf_reduce(
        const double* __restrict__ partial, float* __restrict__ out) {
    double s = 0.0;
    for (int i = threadIdx.x; i < NBLOCK; i += 256)
        s += partial[i];
    for (int off = 32; off > 0; off >>= 1)
        s += __shfl_down(s, off);
    __shared__ double sdata[4];
    const int lane = threadIdx.x & 63;
    const int wv = threadIdx.x >> 6;
    if (lane == 0) sdata[wv] = s;
    __syncthreads();
    if (threadIdx.x == 0) {
        double t = sdata[0] + sdata[1] + sdata[2] + sdata[3];
        out[0] = (float)(t * (1.0 / ((double)HW * BATCH * 4)));
    }
}

extern "C" void kernel_launch(void* const* d_in, const int* in_sizes, int n_in,
                              void* d_out, int out_size, void* d_ws, size_t ws_size,
                              hipStream_t stream) {
    const float* y_pr = (const float*)d_in[0];
    // d_in[1] (y_gt) unused by the reference
    const float* image = (const float*)d_in[2];
    const int* image_class = (const int*)d_in[3];
    float* out = (float*)d_out;
    double* partial = (double*)d_ws;   // NBLOCK doubles = 8 KB

    crf_map<<<NBLOCK, 256, 0, stream>>>(y_pr, image, image_class, partial);
    crf_reduce<<<1, 256, 0, stream>>>(partial, out);
}